// Round 1
// baseline (3888.338 us; speedup 1.0000x reference)
//
#include <hip/hip_runtime.h>

// QRNN: T=512, B=32, D=1024, Q=256.
//  Phase A (prep):  build WhT/UhT fp16 [e][d] (transposed) from quaternion blocks; zero flags.
//  Phase B (gemm):  wh_out = x @ Wh + b  -> written fp32 into d_out (overwritten by scan).
//  Phase C (scan):  h_t = tanh(wh_out[t] + h_{t-1} @ Uh), in-place on d_out.
//      64 WGs = 2 row-groups x 32 col-groups; 128 thr/WG (2 waves x 16 cols).
//      R2 changes vs R1-best (3007us scan):
//        * per-WAVE monotonic flags (flag = t+1, never reset) -> NO __syncthreads in t-loop,
//          waves fully decoupled; consumers poll 64 flags with 64 lanes (lane l <-> producer-wave l).
//        * wh[t+1] prefetched DURING step t (issued after data loads, completes under the
//          end-of-step drain) -> poll loop no longer waits on HBM wh loads via in-order vmcnt.
//        * 4 accumulators (dep-chain 16 -> 8), publish skipped at t=511.
//      All inter-WG traffic via per-access coherent ops (sc0 sc1 -> LLC). No agent fences.

#define TT 512
#define BB 32
#define DD 1024

typedef _Float16 f16;
typedef _Float16 f16x8 __attribute__((ext_vector_type(8)));
typedef _Float16 f16x4 __attribute__((ext_vector_type(4)));
typedef float f32x4 __attribute__((ext_vector_type(4)));

__device__ __constant__ int   QCOMP[4][4] = {{0,1,2,3},{1,0,3,2},{2,3,0,1},{3,2,1,0}};
__device__ __constant__ float QSIGN[4][4] = {{ 1.f, 1.f, 1.f, 1.f},
                                             {-1.f, 1.f, 1.f,-1.f},
                                             {-1.f,-1.f, 1.f, 1.f},
                                             {-1.f, 1.f,-1.f, 1.f}};

__device__ __forceinline__ float qpick(int cmp, const float* a, const float* b,
                                       const float* c, const float* d, int idx) {
    const float* s = (cmp == 0) ? a : (cmp == 1) ? b : (cmp == 2) ? c : d;
    return s[idx];
}

// ---------------- Phase A -------------------------------------------------------------
__global__ void qrnn_prep(const float* __restrict__ wr, const float* __restrict__ wi,
                          const float* __restrict__ wj, const float* __restrict__ wk,
                          const float* __restrict__ ur, const float* __restrict__ ui,
                          const float* __restrict__ uj, const float* __restrict__ uk,
                          f16* __restrict__ WhT, f16* __restrict__ UhT,
                          int* __restrict__ flags)
{
    int bid = blockIdx.x;
    int gid = bid * 256 + threadIdx.x;
    if (bid < 4096) {                    // WhT: 1M elements, flat = e*1024 + d
        int e = gid >> 10, d = gid & 1023;
        int bc = e >> 8, j = e & 255, br = d >> 8, i = d & 255;
        float v = QSIGN[br][bc] * qpick(QCOMP[br][bc], wr, wi, wj, wk, i * 256 + j);
        WhT[gid] = (f16)v;
    } else if (bid < 8192) {             // UhT
        int g = gid - 4096 * 256;
        int e = g >> 10, d = g & 1023;
        int bc = e >> 8, j = e & 255, br = d >> 8, i = d & 255;
        float v = QSIGN[br][bc] * qpick(QCOMP[br][bc], ur, ui, uj, uk, i * 256 + j);
        UhT[g] = (f16)v;
    } else {                             // flags: 2 row-groups x 64 producer-waves, monotonic
        if (threadIdx.x < 128) flags[threadIdx.x] = 0;
    }
}

// ---------------- Phase B: wh_out = x @ Wh + bias ------------------------------------
__global__ __launch_bounds__(256) void qrnn_gemm(const float* __restrict__ x,
                                                 const f16* __restrict__ WhT,
                                                 const float* __restrict__ bias,
                                                 float* __restrict__ out)
{
    __shared__ f16 Ash[128][72];
    __shared__ f16 Bsh[128][72];

    const int tn = blockIdx.x, tm = blockIdx.y;
    const int tid = threadIdx.x;
    const int lane = tid & 63, w = tid >> 6;
    const int wm = (w >> 1) * 64, wn = (w & 1) * 64;
    const int m0 = tm * 128, n0 = tn * 128;
    const int l15 = lane & 15, q8 = (lane >> 4) * 8;

    f32x4 acc[4][4] = {};

    const int arow = tid >> 4;
    const int acol = (tid & 15) * 4;
    const int brow = tid >> 3;
    const int bcol = (tid & 7) * 8;

    for (int kb = 0; kb < DD; kb += 64) {
        #pragma unroll
        for (int p = 0; p < 8; ++p) {
            int rrow = p * 16 + arow;
            float4 v = *(const float4*)(x + (size_t)(m0 + rrow) * DD + kb + acol);
            f16x4 hv = {(f16)v.x, (f16)v.y, (f16)v.z, (f16)v.w};
            *(f16x4*)&Ash[rrow][acol] = hv;
        }
        #pragma unroll
        for (int p = 0; p < 4; ++p) {
            int rn = p * 32 + brow;
            f16x8 v = *(const f16x8*)(WhT + (size_t)(n0 + rn) * DD + kb + bcol);
            *(f16x8*)&Bsh[rn][bcol] = v;
        }
        __syncthreads();
        #pragma unroll
        for (int ks = 0; ks < 64; ks += 32) {
            f16x8 af[4], bf[4];
            #pragma unroll
            for (int i = 0; i < 4; ++i) af[i] = *(const f16x8*)&Ash[wm + i * 16 + l15][ks + q8];
            #pragma unroll
            for (int i = 0; i < 4; ++i) bf[i] = *(const f16x8*)&Bsh[wn + i * 16 + l15][ks + q8];
            #pragma unroll
            for (int i = 0; i < 4; ++i)
                #pragma unroll
                for (int j = 0; j < 4; ++j)
                    acc[i][j] = __builtin_amdgcn_mfma_f32_16x16x32_f16(af[i], bf[j], acc[i][j], 0, 0, 0);
        }
        __syncthreads();
    }
    const int quad = lane >> 4;
    #pragma unroll
    for (int i = 0; i < 4; ++i)
        #pragma unroll
        for (int j = 0; j < 4; ++j) {
            int col = n0 + wn + j * 16 + l15;
            float bz = bias[col];
            #pragma unroll
            for (int rr = 0; rr < 4; ++rr) {
                int row = m0 + wm + i * 16 + quad * 4 + rr;
                out[(size_t)row * DD + col] = acc[i][j][rr] + bz;
            }
        }
}

// ---------------- Phase C: sequential scan -------------------------------------------
// WG (r,c): batch rows [16r,16r+16), cols [32c,32c+32). Wave w: 16 cols.
// Per-wave monotonic flags; zero intra-loop syncthreads; wh prefetched one step ahead.
__global__ __launch_bounds__(128, 1) void qrnn_scan(const f16* __restrict__ UhT,
                                                    unsigned int* __restrict__ hbuf,
                                                    int* __restrict__ flags,
                                                    float* __restrict__ out)
{
    __shared__ f16 Ush[32][1032];   // 32 cols x 1024 k, +8 pad (2-way bank alias = free)

    const int r = blockIdx.x >> 5;          // row group 0..1
    const int c = blockIdx.x & 31;          // col group 0..31
    const int tid = threadIdx.x;
    const int w = tid >> 6, lane = tid & 63;
    const int l15 = lane & 15, quad = lane >> 4, q8 = quad * 8;
    const int dcol = c * 32 + w * 16 + l15; // output feature col (D-frag n)
    const int bq = r * 16 + quad * 4;       // first output batch row (D-frag)

    // stage Uh slice -> LDS: each thread 256 halves of one row
    {
        const int nl = tid >> 2, k0 = (tid & 3) * 256;
        const f16* src = UhT + (size_t)(c * 32 + nl) * DD + k0;
        #pragma unroll
        for (int p = 0; p < 32; ++p)
            *(f16x8*)&Ush[nl][k0 + p * 8] = *(const f16x8*)(src + p * 8);
    }
    __syncthreads();   // only barrier in the kernel

    const int nloc = w * 16 + l15;          // local col for B-frag reads

    // comm buffer geometry (fp16 elements addressed via u32/u64)
    // element idx = row*1024 + k ; byte = idx*2 ; buffers at parity*65536 bytes
    char* hb = (char*)hbuf;
    const char* harow = hb + (size_t)((r * 16 + l15) * 1024 + q8) * 2;  // A[m][k] m=l15
    char* hwrow = hb + (size_t)(bq * 1024 + (dcol & ~1)) * 2;           // packed u32 store base

    // flags: one int per producer WAVE, monotonic (= last published t+1)
    int* myflag = flags + (r << 6) + (c << 1) + w;
    const int* pollflag = flags + (r << 6) + lane;   // lane l <-> producer-wave l

    // wh for t=0 (later steps get it via in-step prefetch)
    float wh[4];
    #pragma unroll
    for (int i = 0; i < 4; ++i) wh[i] = out[(size_t)bq * DD + dcol + (size_t)i * DD];

    #pragma unroll 1
    for (int t = 0; t < TT; ++t) {
        const size_t obase = (size_t)t * (BB * DD) + (size_t)bq * DD + dcol;

        f32x4 acc[4] = {};
        if (t > 0) {
            // wait until all 64 producer-waves of this row group published h_{t-1}
            while (__hip_atomic_load(pollflag, __ATOMIC_RELAXED, __HIP_MEMORY_SCOPE_AGENT) < t) {}

            const char* ha = harow + ((t - 1) & 1) * 65536;
            #pragma unroll
            for (int u = 0; u < 32; ++u) {
                union { unsigned long long q[2]; f16x8 v; } uu;
                uu.q[0] = __hip_atomic_load((const unsigned long long*)(ha + u * 64),
                                            __ATOMIC_RELAXED, __HIP_MEMORY_SCOPE_AGENT);
                uu.q[1] = __hip_atomic_load((const unsigned long long*)(ha + u * 64 + 8),
                                            __ATOMIC_RELAXED, __HIP_MEMORY_SCOPE_AGENT);
                f16x8 bf = *(const f16x8*)&Ush[nloc][u * 32 + q8];
                acc[u & 3] = __builtin_amdgcn_mfma_f32_16x16x32_f16(uu.v, bf, acc[u & 3], 0, 0, 0);
            }
        }

        // prefetch wh for step t+1 NOW (after data loads issued): completes under the
        // end-of-step drain, so next iteration's poll/epilogue pay zero wh latency.
        __builtin_amdgcn_sched_barrier(0);   // keep these AFTER the data loads (in-order vmcnt)
        float whn[4] = {0.f, 0.f, 0.f, 0.f};
        if (t + 1 < TT) {
            const float* nx = out + obase + (size_t)(BB * DD);
            #pragma unroll
            for (int i = 0; i < 4; ++i) whn[i] = nx[(size_t)i * DD];
        }

        // epilogue: h = tanh(acc + wh); fp32 -> d_out (cached), fp16 packed -> hbuf (coherent)
        char* hwp = hwrow + (t & 1) * 65536;
        #pragma unroll
        for (int i = 0; i < 4; ++i) {
            float z = (acc[0][i] + acc[1][i]) + (acc[2][i] + acc[3][i]) + wh[i];
            float e = __expf(2.0f * z);
            float hv = 1.0f - 2.0f * __builtin_amdgcn_rcpf(e + 1.0f);
            out[obase + (size_t)i * DD] = hv;
            if (t < TT - 1) {
                f16 hh = (f16)hv;
                unsigned short hbits = __builtin_bit_cast(unsigned short, hh);
                int other = __shfl_xor((int)hbits, 1, 64);   // partner col (l15 ^ 1)
                if ((lane & 1) == 0) {
                    unsigned int packed = (unsigned int)hbits | ((unsigned int)other << 16);
                    __hip_atomic_store((unsigned int*)(hwp + (size_t)i * 2048), packed,
                                       __ATOMIC_RELAXED, __HIP_MEMORY_SCOPE_AGENT);
                }
            }
        }
        if (t < TT - 1) {
            // per-wave drain (vmcnt is per-wave): our coherent stores are at LLC, then flag.
            asm volatile("s_waitcnt vmcnt(0)" ::: "memory");
            if (lane == 0)
                __hip_atomic_store(myflag, t + 1, __ATOMIC_RELAXED, __HIP_MEMORY_SCOPE_AGENT);
        }
        #pragma unroll
        for (int i = 0; i < 4; ++i) wh[i] = whn[i];
    }
}

extern "C" void kernel_launch(void* const* d_in, const int* in_sizes, int n_in,
                              void* d_out, int out_size, void* d_ws, size_t ws_size,
                              hipStream_t stream)
{
    const float* x  = (const float*)d_in[0];
    const float* wr = (const float*)d_in[1];
    const float* wi = (const float*)d_in[2];
    const float* wj = (const float*)d_in[3];
    const float* wk = (const float*)d_in[4];
    const float* ur = (const float*)d_in[5];
    const float* ui = (const float*)d_in[6];
    const float* uj = (const float*)d_in[7];
    const float* uk = (const float*)d_in[8];
    const float* bias = (const float*)d_in[9];
    float* out = (float*)d_out;

    char* ws = (char*)d_ws;
    f16* WhT  = (f16*)(ws);                          // 2 MB
    f16* UhT  = (f16*)(ws + (1 << 21));              // 2 MB
    unsigned int* hbuf = (unsigned int*)(ws + (1 << 22));      // 2 x 64 KB
    int* flags = (int*)(ws + (1 << 22) + (1 << 17)); // 128 ints (monotonic)

    hipLaunchKernelGGL(qrnn_prep, dim3(8193), dim3(256), 0, stream,
                       wr, wi, wj, wk, ur, ui, uj, uk, WhT, UhT, flags);
    hipLaunchKernelGGL(qrnn_gemm, dim3(8, 128), dim3(256), 0, stream,
                       x, WhT, bias, out);
    hipLaunchKernelGGL(qrnn_scan, dim3(64), dim3(128), 0, stream,
                       UhT, hbuf, flags, out);
}